// Round 9
// baseline (3321.558 us; speedup 1.0000x reference)
//
#include <hip/hip_runtime.h>
#include <hip/hip_fp16.h>
#include <math.h>

#define N_NODES 100000
#define N_EDGES 1600000
#define MAX_ITER 50
#define THRESH 0.01f
#define SCAN_CHUNK 1024
#define NBLK_SCAN 98            // ceil(100000/1024)
#define NB_EDGE ((N_EDGES + 255) / 256)
#define SLOTS_W 320             // slots per wave
#define GROUPS 5                // 5 groups of 64
#define WAVES_TOTAL 5000        // 1.6M / 320
#define BLK_PIPE 1250           // 5000 waves / 4 per block

// ---------------- ws layout (total 52 MB; harness provides >=103 MB) ------
//   off   : 0           (N+1 ints)        -> pad 400,128
//   cnt   : 400,128     (N ints)          -> 800,128
//   flags : 800,128     (51 + kcnt ints)  -> pad 800,384
//   wc    : 800,384     (295 f32 weights) -> pad 801,664
//   buf0  : 801,664     (N*8 f32 state, stride 8)
//   buf1  : 4,001,664
//   rowsg : 7,201,664   (E ints, row per CSR slot)
//   sv    : 13,601,664  (E int2: src, arc_val bits)
//   featr : 26,401,664  (E * 16 B: 8 fp16 edge feats, CSR order) [bsum scratch]

__device__ __forceinline__ float fast_tanh(float x) {
    float ax = fabsf(x);
    float e = __expf(2.0f * ax);
    float r = 1.0f - 2.0f * __builtin_amdgcn_rcpf(e + 1.0f);
    return copysignf(r, x);
}

__global__ void zero_ints(int* p, int n) {
    int i = blockIdx.x * blockDim.x + threadIdx.x;
    if (i < n) p[i] = 0;
}

__global__ void zero_floats(float* p, int n) {
    int i = blockIdx.x * blockDim.x + threadIdx.x;
    if (i < n) p[i] = 0.f;
}

__global__ void hist_kernel(const int* __restrict__ rows, int* __restrict__ cnt) {
    int e = blockIdx.x * blockDim.x + threadIdx.x;
    if (e < N_EDGES) atomicAdd(&cnt[rows[e]], 1);
}

__global__ __launch_bounds__(256) void scan1_kernel(const int* __restrict__ cnt,
                                                    int* __restrict__ off,
                                                    int* __restrict__ bsum) {
    __shared__ int sm[256];
    int b = blockIdx.x, t = threadIdx.x;
    int base = b * SCAN_CHUNK + t * 4;
    int v[4];
    int tsum = 0;
#pragma unroll
    for (int j = 0; j < 4; ++j) {
        v[j] = (base + j < N_NODES) ? cnt[base + j] : 0;
        tsum += v[j];
    }
    int val = tsum;
    sm[t] = val;
    __syncthreads();
    for (int d = 1; d < 256; d <<= 1) {
        int x = (t >= d) ? sm[t - d] : 0;
        __syncthreads();
        val += x;
        sm[t] = val;
        __syncthreads();
    }
    int run = val - tsum;
#pragma unroll
    for (int j = 0; j < 4; ++j) {
        if (base + j < N_NODES) off[base + j] = run;
        run += v[j];
    }
    if (t == 255) bsum[b] = val;
}

__global__ __launch_bounds__(128) void scan2_kernel(int* __restrict__ bsum) {
    __shared__ int sm[128];
    int t = threadIdx.x;
    int v = (t < NBLK_SCAN) ? bsum[t] : 0;
    int val = v;
    sm[t] = val;
    __syncthreads();
    for (int d = 1; d < 128; d <<= 1) {
        int x = (t >= d) ? sm[t - d] : 0;
        __syncthreads();
        val += x;
        sm[t] = val;
        __syncthreads();
    }
    if (t < NBLK_SCAN) bsum[t] = val - v;
}

__global__ __launch_bounds__(256) void scan3_kernel(int* __restrict__ off,
                                                    const int* __restrict__ bsum) {
    int b = blockIdx.x, t = threadIdx.x;
    int add = bsum[b];
    int base = b * SCAN_CHUNK + t * 4;
#pragma unroll
    for (int j = 0; j < 4; ++j)
        if (base + j < N_NODES) off[base + j] += add;
    if (b == 0 && t == 0) off[N_NODES] = N_EDGES;
}

// wc layout: [0..74] W1S[j*5+i]=W1[(8+i)*15+j] | [75..149] W2T[j*15+i]=W2[i*5+j]
//            [150..154] b2 | [160..279] W1F[j*8+i]=W1[i*15+j] | [280..294] b1
__global__ void wprep_kernel(const float* __restrict__ W1, const float* __restrict__ b1,
                             const float* __restrict__ W2, const float* __restrict__ b2,
                             float* __restrict__ wc) {
    int t = threadIdx.x;
    for (int idx = t; idx < 75; idx += 256) { int j = idx / 5, i = idx % 5; wc[idx] = W1[(8 + i) * 15 + j]; }
    for (int idx = t; idx < 75; idx += 256) { int j = idx / 15, i = idx % 15; wc[75 + idx] = W2[i * 5 + j]; }
    for (int idx = t; idx < 5; idx += 256) wc[150 + idx] = b2[idx];
    for (int idx = t; idx < 120; idx += 256) { int j = idx / 8, i = idx % 8; wc[160 + idx] = W1[i * 15 + j]; }
    for (int idx = t; idx < 15; idx += 256) wc[280 + idx] = b1[idx];
}

union F8Pack { __half2 h2[4]; uint4 u4; };

// Fused build: sequential edge reads, fp16 feature pack, scattered CSR write.
__global__ __launch_bounds__(256) void scatter_build3(
    const int* __restrict__ rows, const int* __restrict__ esrc,
    const float* __restrict__ avals, const float* __restrict__ efeat,
    const int* __restrict__ off, int* __restrict__ cur,
    uint4* __restrict__ featr, int2* __restrict__ sv, int* __restrict__ rowsg) {
    int e = blockIdx.x * blockDim.x + threadIdx.x;
    if (e >= N_EDGES) return;
    int r = rows[e];
    int p = off[r] + atomicAdd(&cur[r], 1);
    const float4* fp = (const float4*)(efeat + (size_t)e * 8);
    float4 f0 = fp[0], f1 = fp[1];
    F8Pack pk;
    pk.h2[0] = __floats2half2_rn(f0.x, f0.y);
    pk.h2[1] = __floats2half2_rn(f0.z, f0.w);
    pk.h2[2] = __floats2half2_rn(f1.x, f1.y);
    pk.h2[3] = __floats2half2_rn(f1.z, f1.w);
    featr[p] = pk.u4;
    sv[p] = make_int2(esrc[e], __float_as_int(avals[e]));
    rowsg[p] = r;
}

__global__ void init_state8_kernel(const float* __restrict__ state_init,
                                   const float* __restrict__ old_init,
                                   float* __restrict__ buf0,
                                   int* __restrict__ flags) {
    int n = blockIdx.x * blockDim.x + threadIdx.x;
    if (n >= N_NODES) return;
    float ss = 0.f;
    float s[5];
#pragma unroll
    for (int j = 0; j < 5; ++j) {
        s[j] = state_init[n * 5 + j];
        float d = s[j] - old_init[n * 5 + j];
        ss += d * d;
    }
    ((float4*)(buf0 + (size_t)n * 8))[0] = make_float4(s[0], s[1], s[2], s[3]);
    ((float4*)(buf0 + (size_t)n * 8))[1] = make_float4(s[4], 0.f, 0.f, 0.f);
    int pred = sqrtf(ss + 1e-11f) > THRESH;
    unsigned long long m = __ballot(pred);
    if ((threadIdx.x & 63) == 0 && m) atomicOr(&flags[0], 1);
}

// ---- hot kernel: persistent waves, 320 slots/wave, 2-level pipeline,
//      fp16 features + in-kernel layer1, ballot segmented scan, reg carry ----
__global__ __launch_bounds__(256) void edge_pipe_kernel(
    const int* __restrict__ rowsg, const uint4* __restrict__ featr,
    const int2* __restrict__ sv,
    const float* __restrict__ sprev, float* __restrict__ snext,
    const float* __restrict__ wc, const int* __restrict__ flag_cur) {
    if (*flag_cur == 0) return;
    int gtid = blockIdx.x * 256 + threadIdx.x;
    int wid = gtid >> 6;
    int lane = threadIdx.x & 63;
    if (wid >= WAVES_TOTAL) return;
    int base = wid * SLOTS_W;

    int head_prev = (wid > 0) ? rowsg[base - 1] : -2;
    int tail_next = (wid < WAVES_TOTAL - 1) ? rowsg[base + SLOTS_W] : -2;

    const float* W1S = wc;        // [15][5]
    const float* W2T = wc + 75;   // [5][15]
    const float* B2  = wc + 150;
    const float* W1F = wc + 160;  // [15][8]
    const float* B1  = wc + 280;

    int carry_row = -1;
    bool carry_head = false;
    float cv0 = 0, cv1 = 0, cv2 = 0, cv3 = 0, cv4 = 0;

    // ---- pipeline preload ----
    int p0 = base + lane;
    int2 s0m = sv[p0];            int r0v = rowsg[p0];
    int2 s1m = sv[p0 + 64];       int r1v = rowsg[p0 + 64];
    float4 g0a = ((const float4*)(sprev + (size_t)s0m.x * 8))[0];
    float  g0b = sprev[(size_t)s0m.x * 8 + 4];
    uint4 f0r = featr[p0];

    for (int k = 0; k < GROUPS; ++k) {
        // stage: meta for group k+2
        int2 s2m; int r2v;
        if (k + 2 < GROUPS) {
            int p2 = base + (k + 2) * 64 + lane;
            s2m = sv[p2]; r2v = rowsg[p2];
        }
        // stage: gather + features for group k+1
        float4 g1a; float g1b; uint4 f1r;
        if (k + 1 < GROUPS) {
            int p1 = base + (k + 1) * 64 + lane;
            g1a = ((const float4*)(sprev + (size_t)s1m.x * 8))[0];
            g1b = sprev[(size_t)s1m.x * 8 + 4];
            f1r = featr[p1];
        }
        // ---- compute group k ----
        int r = r0v;
        float av = __int_as_float(s0m.y);
        F8Pack pk; pk.u4 = f0r;
        float f[8];
#pragma unroll
        for (int j = 0; j < 4; ++j) {
            float2 x = __half22float2(pk.h2[j]);
            f[2 * j] = x.x; f[2 * j + 1] = x.y;
        }
        float h1[15];
#pragma unroll
        for (int j = 0; j < 15; ++j) {
            float a = B1[j];
#pragma unroll
            for (int i = 0; i < 8; ++i) a += f[i] * W1F[j * 8 + i];
            a += g0a.x * W1S[j * 5 + 0];
            a += g0a.y * W1S[j * 5 + 1];
            a += g0a.z * W1S[j * 5 + 2];
            a += g0a.w * W1S[j * 5 + 3];
            a += g0b  * W1S[j * 5 + 4];
            h1[j] = fast_tanh(a);
        }
        float v0, v1, v2, v3, v4;
        {
            float o[5];
#pragma unroll
            for (int j = 0; j < 5; ++j) {
                float a = B2[j];
#pragma unroll
                for (int i = 0; i < 15; ++i) a += h1[i] * W2T[j * 15 + i];
                o[j] = fast_tanh(a) * av;
            }
            v0 = o[0]; v1 = o[1]; v2 = o[2]; v3 = o[3]; v4 = o[4];
        }
        // ---- ballot-based segmented inclusive scan (rows non-decreasing) ----
        int rprev = __shfl_up(r, 1, 64);
        bool head = (lane == 0) || (rprev != r);
        unsigned long long hm = __ballot(head);
        unsigned long long below = hm & (0xFFFFFFFFFFFFFFFFULL >> (63 - lane));
        int segstart = 63 - __clzll(below);
#pragma unroll
        for (int d = 1; d < 64; d <<= 1) {
            float t0 = __shfl_up(v0, d, 64);
            float t1 = __shfl_up(v1, d, 64);
            float t2 = __shfl_up(v2, d, 64);
            float t3 = __shfl_up(v3, d, 64);
            float t4 = __shfl_up(v4, d, 64);
            if (lane - d >= segstart) { v0 += t0; v1 += t1; v2 += t2; v3 += t3; v4 += t4; }
        }
        bool next_head = (lane < 63) && ((hm >> (lane + 1)) & 1ULL);
        bool is_tail = (lane == 63) || next_head;
        int r_next_first = (k + 1 < GROUPS) ? __shfl(r1v, 0, 64) : -3;

        float w0 = v0, w1 = v1, w2 = v2, w3 = v3, w4 = v4;
        if (is_tail && r == carry_row) { w0 += cv0; w1 += cv1; w2 += cv2; w3 += cv3; w4 += cv4; }
        bool rh = (r == carry_row && carry_head) || (k == 0 && head_prev == r);
        bool cont = is_tail && (lane == 63) && (k + 1 < GROUPS) && (r == r_next_first);
        if (is_tail && !cont) {
            bool wec = (lane == 63) && (k == GROUPS - 1) && (r == tail_next);
            float* dst = snext + (size_t)r * 8;
            if (rh || wec) {
                atomicAdd(dst + 0, w0);
                atomicAdd(dst + 1, w1);
                atomicAdd(dst + 2, w2);
                atomicAdd(dst + 3, w3);
                atomicAdd(dst + 4, w4);
            } else {
                ((float4*)dst)[0] = make_float4(w0, w1, w2, w3);
                dst[4] = w4;
            }
        }
        // carry from lane 63
        int cont63 = __shfl((int)cont, 63, 64);
        int cr63 = __shfl(r, 63, 64);
        int ch63 = __shfl((int)rh, 63, 64);
        float nc0 = __shfl(w0, 63, 64);
        float nc1 = __shfl(w1, 63, 64);
        float nc2 = __shfl(w2, 63, 64);
        float nc3 = __shfl(w3, 63, 64);
        float nc4 = __shfl(w4, 63, 64);
        carry_row = cont63 ? cr63 : -1;
        carry_head = cont63 && ch63;
        cv0 = nc0; cv1 = nc1; cv2 = nc2; cv3 = nc3; cv4 = nc4;
        // rotate pipeline
        s0m = s1m; r0v = r1v; g0a = g1a; g0b = g1b; f0r = f1r;
        s1m = s2m; r1v = r2v;
    }
}

// Per-node: convergence flag, kcnt, inactive-copy; zeroes sp for next iter.
__global__ void node_pass_kernel(float* __restrict__ sp, float* __restrict__ sn,
                                 const int* __restrict__ flag_cur,
                                 int* __restrict__ flag_next,
                                 int* __restrict__ kcnt) {
    int n = blockIdx.x * blockDim.x + threadIdx.x;
    if (n >= N_NODES) return;
    bool active = (*flag_cur != 0);
    float4 o0 = ((const float4*)(sp + (size_t)n * 8))[0];
    float o4 = sp[(size_t)n * 8 + 4];
    int pred = 0;
    if (active) {
        if (n == 0) *kcnt += 1;
        float4 s0 = ((const float4*)(sn + (size_t)n * 8))[0];
        float s4 = sn[(size_t)n * 8 + 4];
        float d0 = s0.x - o0.x, d1 = s0.y - o0.y, d2 = s0.z - o0.z;
        float d3 = s0.w - o0.w, d4 = s4 - o4;
        float ss = d0 * d0 + d1 * d1 + d2 * d2 + d3 * d3 + d4 * d4;
        pred = sqrtf(ss + 1e-11f) > THRESH;
    } else {
        ((float4*)(sn + (size_t)n * 8))[0] = o0;
        sn[(size_t)n * 8 + 4] = o4;
    }
    ((float4*)(sp + (size_t)n * 8))[0] = make_float4(0.f, 0.f, 0.f, 0.f);
    sp[(size_t)n * 8 + 4] = 0.f;
    unsigned long long m = __ballot(pred);
    if ((threadIdx.x & 63) == 0 && m) atomicOr(flag_next, 1);
}

__global__ void final8_kernel(const float* __restrict__ state,
                              const float* __restrict__ W3, const float* __restrict__ b3,
                              const float* __restrict__ W4, const float* __restrict__ b4,
                              const int* __restrict__ kcnt,
                              float* __restrict__ out) {
    int n = blockIdx.x * blockDim.x + threadIdx.x;
    if (n == 0) out[(size_t)N_NODES * 7] = (float)(*kcnt);
    if (n >= N_NODES) return;
    float st[5];
    float4 s0 = ((const float4*)(state + (size_t)n * 8))[0];
    st[0] = s0.x; st[1] = s0.y; st[2] = s0.z; st[3] = s0.w;
    st[4] = state[(size_t)n * 8 + 4];
    float o1[10];
#pragma unroll
    for (int j = 0; j < 10; ++j) {
        float a = b3[j];
#pragma unroll
        for (int i = 0; i < 5; ++i) a += st[i] * W3[i * 10 + j];
        o1[j] = tanhf(a);
    }
    float z[7];
    float m = -1e30f;
#pragma unroll
    for (int j = 0; j < 7; ++j) {
        float a = b4[j];
#pragma unroll
        for (int i = 0; i < 10; ++i) a += o1[i] * W4[i * 7 + j];
        z[j] = a;
        m = fmaxf(m, a);
    }
    float s = 0.f;
#pragma unroll
    for (int j = 0; j < 7; ++j) { z[j] = expf(z[j] - m); s += z[j]; }
    float inv = 1.f / s;
#pragma unroll
    for (int j = 0; j < 7; ++j) out[(size_t)n * 7 + j] = z[j] * inv;
}

extern "C" void kernel_launch(void* const* d_in, const int* in_sizes, int n_in,
                              void* d_out, int out_size, void* d_ws, size_t ws_size,
                              hipStream_t stream) {
    const float* edge_feat  = (const float*)d_in[0];
    const int*   edge_src   = (const int*)d_in[1];
    const int*   arc_rows   = (const int*)d_in[2];
    const float* arc_vals   = (const float*)d_in[3];
    const float* state_init = (const float*)d_in[4];
    const float* old_init   = (const float*)d_in[5];
    const float* W1 = (const float*)d_in[6];
    const float* b1 = (const float*)d_in[7];
    const float* W2 = (const float*)d_in[8];
    const float* b2 = (const float*)d_in[9];
    const float* W3 = (const float*)d_in[10];
    const float* b3 = (const float*)d_in[11];
    const float* W4 = (const float*)d_in[12];
    const float* b4 = (const float*)d_in[13];

    char* ws = (char*)d_ws;
    int*   off   = (int*)(ws + 0);
    int*   cnt   = (int*)(ws + 400128);
    int*   flags = (int*)(ws + 800128);
    int*   kcnt  = flags + 51;
    float* wc    = (float*)(ws + 800384);
    float* buf0  = (float*)(ws + 801664);
    float* buf1  = (float*)(ws + 4001664);
    int*   rowsg = (int*)(ws + 7201664);
    int2*  sv    = (int2*)(ws + 13601664);
    uint4* featr = (uint4*)(ws + 26401664);
    int*   bsum  = (int*)(ws + 26401664);  // scratch; dead before featr written

    int nb = (N_NODES + 255) / 256;
    int eb = NB_EDGE;

    // ---- one-time CSR + record build ----
    hipLaunchKernelGGL(zero_ints, dim3(nb), dim3(256), 0, stream, cnt, N_NODES);
    hipLaunchKernelGGL(zero_ints, dim3(1), dim3(64), 0, stream, flags, 52);
    hipLaunchKernelGGL(hist_kernel, dim3(eb), dim3(256), 0, stream, arc_rows, cnt);
    hipLaunchKernelGGL(scan1_kernel, dim3(NBLK_SCAN), dim3(256), 0, stream, cnt, off, bsum);
    hipLaunchKernelGGL(scan2_kernel, dim3(1), dim3(128), 0, stream, bsum);
    hipLaunchKernelGGL(scan3_kernel, dim3(NBLK_SCAN), dim3(256), 0, stream, off, bsum);
    hipLaunchKernelGGL(zero_ints, dim3(nb), dim3(256), 0, stream, cnt, N_NODES);
    hipLaunchKernelGGL(wprep_kernel, dim3(1), dim3(256), 0, stream, W1, b1, W2, b2, wc);
    hipLaunchKernelGGL(scatter_build3, dim3(eb), dim3(256), 0, stream,
                       arc_rows, edge_src, arc_vals, edge_feat, off, cnt, featr, sv, rowsg);
    hipLaunchKernelGGL(init_state8_kernel, dim3(nb), dim3(256), 0, stream,
                       state_init, old_init, buf0, flags);
    hipLaunchKernelGGL(zero_floats, dim3((N_NODES * 8 + 255) / 256), dim3(256), 0, stream,
                       buf1, N_NODES * 8);

    // ---- 50 iterations: edge_pipe (accumulate into pre-zeroed sn) + node_pass ----
    for (int it = 0; it < MAX_ITER; ++it) {
        float* sp = (it & 1) ? buf1 : buf0;
        float* sn = (it & 1) ? buf0 : buf1;
        hipLaunchKernelGGL(edge_pipe_kernel, dim3(BLK_PIPE), dim3(256), 0, stream,
                           rowsg, featr, sv, sp, sn, wc, flags + it);
        hipLaunchKernelGGL(node_pass_kernel, dim3(nb), dim3(256), 0, stream,
                           sp, sn, flags + it, flags + it + 1, kcnt);
    }

    hipLaunchKernelGGL(final8_kernel, dim3(nb), dim3(256), 0, stream,
                       buf0, W3, b3, W4, b4, kcnt, (float*)d_out);
}